// Round 8
// baseline (329.246 us; speedup 1.0000x reference)
//
#include <hip/hip_runtime.h>

typedef unsigned short u16;
typedef __attribute__((ext_vector_type(8))) short bf16x8;   // 8 bf16 = 4 VGPR
typedef __attribute__((ext_vector_type(4))) float f32x4;

// Bit-math round-to-nearest-even f32->bf16. NOTE: empirically faster than the
// __bf16 cast path in this kernel (R6/R7 A/B: cast costs ~20us despite fewer
// VALU ops) -- do not "optimize" this back to the hardware cast.
__device__ __forceinline__ u16 f2b(float f){
  unsigned int u = __float_as_uint(f);
  u += 0x7fffu + ((u>>16)&1u);
  return (u16)(u>>16);
}

// ---- K1: LayerNorm over c_m -> bf16 mnb [l][s][cm].
// Block = (l, s-block of 32): writes 16KB contiguous, reads 1KB chunks. ----
__global__ __launch_bounds__(256) void k_ln(const float* __restrict__ m,
    const float* __restrict__ lw, const float* __restrict__ lb,
    u16* __restrict__ mnb){
  int bx = blockIdx.x;                       // 2048 blocks
  int l = bx>>3;
  int s0 = (bx&7)*32 + (threadIdx.x>>6)*8;   // 4 waves x 8 rows
  int ln = threadIdx.x&63;
  float4 w = *(const float4*)(lw + ln*4);
  float4 b = *(const float4*)(lb + ln*4);
  #pragma unroll
  for (int i=0;i<8;++i){
    int s = s0 + i;
    float4 x = *(const float4*)(m + ((size_t)s*256 + l)*256 + ln*4);
    float s1 = x.x+x.y+x.z+x.w;
    float s2 = x.x*x.x + x.y*x.y + x.z*x.z + x.w*x.w;
    #pragma unroll
    for (int off=32; off>0; off>>=1){
      s1 += __shfl_xor(s1, off);
      s2 += __shfl_xor(s2, off);
    }
    float mu  = s1*(1.0f/256.0f);
    float inv = rsqrtf(s2*(1.0f/256.0f) - mu*mu + 1e-5f);
    u16 o[4];
    o[0] = f2b((x.x-mu)*inv*w.x + b.x);
    o[1] = f2b((x.y-mu)*inv*w.y + b.y);
    o[2] = f2b((x.z-mu)*inv*w.z + b.z);
    o[3] = f2b((x.w-mu)*inv*w.w + b.w);
    *(ushort4*)(mnb + ((size_t)l*256 + s)*256 + ln*4) = *(ushort4*)o;
  }
}

// ---- K0: pre-transpose weights to bf16 WT[z][n][cm], coalesced via LDS. ----
__global__ __launch_bounds__(256) void k_wprep(
    const float* __restrict__ wq, const float* __restrict__ wk,
    const float* __restrict__ wv, const float* __restrict__ wg,
    const float* __restrict__ wo, u16* __restrict__ WT){
  __shared__ u16 T[16*264];
  int z = blockIdx.y, n0 = blockIdx.x*16, tid = threadIdx.x;
  const float* W = (z==0)?wq:(z==1)?wk:(z==2)?wv:(z==3)?wg:wo;
  int nl = tid&15;
  #pragma unroll
  for (int i=0;i<16;++i){
    int cm = i*16 + (tid>>4);
    T[nl*264 + cm] = f2b(W[(size_t)cm*256 + n0 + nl]);   // 64B-coalesced reads
  }
  __syncthreads();
  int n = tid>>4, cc = (tid&15)*16;
  uint4 a = *(const uint4*)&T[n*264 + cc];
  uint4 c = *(const uint4*)&T[n*264 + cc + 8];
  *(uint4*)&WT[(size_t)z*65536 + (size_t)(n0+n)*256 + cc]     = a;
  *(uint4*)&WT[(size_t)z*65536 + (size_t)(n0+n)*256 + cc + 8] = c;
}

// ---- K2: fully fused per (l,h): QKV proj -> attention -> gate -> out proj ----
// Out identity: block (l,h) -> out rows (s'=32h+(l>>3), l'=(l&7)*32+j), and
// O_flat[j][n] == o[s][c] at the same flat index (s*32+c == j*256+n).
// == R2 ops/rounding exactly; LDS diet 53760->38400 B => 4 blocks/CU. ==
__global__ __launch_bounds__(256,3) void k_fused(const u16* __restrict__ mnb,
    const u16* __restrict__ WT, const float* __restrict__ bg,
    const float* __restrict__ bo, float* __restrict__ outp){
  // LDS u16 map, total 19200 u16 = 38400 B -> 4 blocks/CU (4x38400<=163840).
  //  SC  per-wave [16][40]  :     0 ..  2559  (q- and P-transpose scratch)
  //  KS  [256][32] k[t][c]  :  2560 .. 10751
  //  VT  [32][264] v^T[c][t]: 10752 .. 19199
  //  OS  f32 [128][32] half : u16 0..8191    (after B1; SC/KS dead)
  //  GS  [32][264] gated    : 10752 .. 19199 (after B1; VT dead)
  __shared__ u16 smem[19200];
  u16* KS = smem + 2560;
  u16* VT = smem + 10752;
  float* OS = (float*)smem;
  u16* GS = smem + 10752;

  int bx = blockIdx.x;
  // XCD-aware swizzle: XCD = bx%8; each XCD owns a contiguous 32-wide l-range,
  // 8 h-blocks per l adjacent in dispatch order.
  int l = ((bx&7)<<5) | (bx>>6);
  int h = (bx>>3)&7;
  int tid = threadIdx.x;
  int lane = tid&63, wid = tid>>6, quad = lane>>4, lo = lane&15;
  int m0 = wid*64;
  u16* SC = smem + wid*640;
  f32x4 z4 = {0.f,0.f,0.f,0.f};

  // ================= Phase 1: QKV projection (head h slice) =================
  const u16* Abase = mnb + (size_t)l*65536;          // mn_l [s][cm]
  const u16* Bq = WT + (size_t)h*32*256;
  const u16* Bk = WT + (size_t)65536 + (size_t)h*32*256;
  const u16* Bv = WT + (size_t)2*65536 + (size_t)h*32*256;
  f32x4 acc[4][6];                                   // nt: 0-1 q, 2-3 k, 4-5 v
  #pragma unroll
  for (int a=0;a<4;++a)
    #pragma unroll
    for (int b=0;b<6;++b) acc[a][b]=z4;

  for (int ks=0; ks<8; ++ks){
    bf16x8 af[4];
    #pragma unroll
    for (int mt=0; mt<4; ++mt)
      af[mt] = *(const bf16x8*)(Abase + (size_t)(m0+mt*16+lo)*256 + ks*32 + quad*8);
    bf16x8 bq[2], bk2[2], bv2[2];
    #pragma unroll
    for (int c2=0; c2<2; ++c2){
      bq[c2]  = *(const bf16x8*)(Bq + (size_t)(c2*16+lo)*256 + ks*32 + quad*8);
      bk2[c2] = *(const bf16x8*)(Bk + (size_t)(c2*16+lo)*256 + ks*32 + quad*8);
      bv2[c2] = *(const bf16x8*)(Bv + (size_t)(c2*16+lo)*256 + ks*32 + quad*8);
    }
    #pragma unroll
    for (int mt=0; mt<4; ++mt){
      #pragma unroll
      for (int c2=0; c2<2; ++c2){
        acc[mt][0+c2] = __builtin_amdgcn_mfma_f32_16x16x32_bf16(af[mt], bq[c2],  acc[mt][0+c2], 0,0,0);
        acc[mt][2+c2] = __builtin_amdgcn_mfma_f32_16x16x32_bf16(af[mt], bk2[c2], acc[mt][2+c2], 0,0,0);
        acc[mt][4+c2] = __builtin_amdgcn_mfma_f32_16x16x32_bf16(af[mt], bv2[c2], acc[mt][4+c2], 0,0,0);
      }
    }
  }
  // scatter k (row-major) and v (transposed) to LDS
  #pragma unroll
  for (int mt=0; mt<4; ++mt)
    #pragma unroll
    for (int ntl=0; ntl<2; ++ntl)
      #pragma unroll
      for (int r=0; r<4; ++r){
        int s = m0 + mt*16 + quad*4 + r;
        KS[s*32 + ntl*16+lo] = f2b(acc[mt][2+ntl][r]);
        VT[(ntl*16+lo)*264 + s] = f2b(acc[mt][4+ntl][r]);
      }
  // q transpose via per-wave scratch (wave-private, no barrier; R5-proven)
  bf16x8 qf[4];
  #pragma unroll
  for (int mt=0; mt<4; ++mt){
    #pragma unroll
    for (int ntl=0; ntl<2; ++ntl)
      #pragma unroll
      for (int r=0; r<4; ++r)
        SC[(quad*4+r)*40 + ntl*16+lo] = f2b(acc[mt][0+ntl][r]);
    qf[mt] = *(const bf16x8*)&SC[lo*40 + quad*8];
  }
  __syncthreads();   // B0: KS/VT visible to all waves

  // ================= Phase 2: attention =====================================
  const float scale = 0.17677669529663687f;  // 1/sqrt(32)
  float lr[16];
  #pragma unroll
  for (int i=0;i<16;++i) lr[i]=0.f;
  f32x4 o_acc[4][2];
  #pragma unroll
  for (int a=0;a<4;++a){ o_acc[a][0]=z4; o_acc[a][1]=z4; }

  for (int ts=0; ts<8; ++ts){
    bf16x8 kf[2];
    #pragma unroll
    for (int ntl=0; ntl<2; ++ntl)
      kf[ntl] = *(const bf16x8*)&KS[(ts*32+ntl*16+lo)*32 + quad*8];
    bf16x8 vf[2];
    #pragma unroll
    for (int nc=0; nc<2; ++nc)
      vf[nc] = *(const bf16x8*)&VT[(nc*16+lo)*264 + ts*32 + quad*8];
    #pragma unroll
    for (int mt=0; mt<4; ++mt){
      f32x4 sa[2];
      sa[0] = __builtin_amdgcn_mfma_f32_16x16x32_bf16(qf[mt], kf[0], z4, 0,0,0);
      sa[1] = __builtin_amdgcn_mfma_f32_16x16x32_bf16(qf[mt], kf[1], z4, 0,0,0);
      #pragma unroll
      for (int ntl=0; ntl<2; ++ntl)
        #pragma unroll
        for (int r=0; r<4; ++r){
          float p = __expf(sa[ntl][r]*scale);
          lr[mt*4+r] += p;
          SC[(quad*4+r)*40 + ntl*16+lo] = f2b(p);
        }
      bf16x8 paf = *(const bf16x8*)&SC[lo*40 + quad*8];
      o_acc[mt][0] = __builtin_amdgcn_mfma_f32_16x16x32_bf16(paf, vf[0], o_acc[mt][0], 0,0,0);
      o_acc[mt][1] = __builtin_amdgcn_mfma_f32_16x16x32_bf16(paf, vf[1], o_acc[mt][1], 0,0,0);
    }
  }
  #pragma unroll
  for (int i=0;i<16;++i){
    float v = lr[i];
    v += __shfl_xor(v, 1);
    v += __shfl_xor(v, 2);
    v += __shfl_xor(v, 4);
    v += __shfl_xor(v, 8);
    lr[i] = 1.0f / v;
  }
  __syncthreads();   // B1: all waves done reading KS/VT/SC

  // ================= Phase 3: gate GEMM [32 x 256], two j-halves ============
  int sp  = h*32 + (l>>3);      // s' (constant per block)
  int l0p = (l&7)*32;           // l' base; rows j = 0..31
  int wn0 = wid*64;             // this wave's 64-col slice of n
  const u16* Gw = WT + (size_t)3*65536;   // wg^T [n][cm]

  // waves 0,1 publish o rows s<128 (f32, same values as R2) into OS half
  if (wid < 2){
    #pragma unroll
    for (int mt=0; mt<4; ++mt)
      #pragma unroll
      for (int nc=0; nc<2; ++nc)
        #pragma unroll
        for (int r=0; r<4; ++r){
          int s = m0 + mt*16 + quad*4 + r;
          OS[s*32 + nc*16+lo] = o_acc[mt][nc][r] * lr[mt*4+r];
        }
  }
  // pass-0 gate ks-loop (rows j=0..15; global loads overlap the OS writes)
  f32x4 gacc0[4];
  #pragma unroll
  for (int b=0;b<4;++b) gacc0[b]=z4;
  for (int ks=0; ks<8; ++ks){
    bf16x8 ga = *(const bf16x8*)(mnb + ((size_t)(l0p+lo)*256 + sp)*256 + ks*32 + quad*8);
    bf16x8 gb[4];
    #pragma unroll
    for (int nt=0; nt<4; ++nt)
      gb[nt] = *(const bf16x8*)(Gw + (size_t)(wn0+nt*16+lo)*256 + ks*32 + quad*8);
    #pragma unroll
    for (int nt=0; nt<4; ++nt)
      gacc0[nt] = __builtin_amdgcn_mfma_f32_16x16x32_bf16(ga, gb[nt], gacc0[nt], 0,0,0);
  }
  __syncthreads();   // B2: OS half-0 visible
  #pragma unroll
  for (int nt=0; nt<4; ++nt){
    int n = wn0 + nt*16 + lo;
    float bgn = bg[n];
    #pragma unroll
    for (int r=0; r<4; ++r){
      int j = quad*4 + r;                       // 0..15
      float g = 1.f/(1.f + __expf(-(gacc0[nt][r] + bgn)));
      int sidx = j*8 + (n>>5);                  // < 128
      GS[j*264 + n] = f2b(g * OS[sidx*32 + (n&31)]);
    }
  }
  __syncthreads();   // B3: pass-0 OS reads complete

  // waves 2,3 publish o rows s>=128
  if (wid >= 2){
    #pragma unroll
    for (int mt=0; mt<4; ++mt)
      #pragma unroll
      for (int nc=0; nc<2; ++nc)
        #pragma unroll
        for (int r=0; r<4; ++r){
          int s = m0 + mt*16 + quad*4 + r - 128;
          OS[s*32 + nc*16+lo] = o_acc[mt][nc][r] * lr[mt*4+r];
        }
  }
  f32x4 gacc1[4];
  #pragma unroll
  for (int b=0;b<4;++b) gacc1[b]=z4;
  for (int ks=0; ks<8; ++ks){
    bf16x8 ga = *(const bf16x8*)(mnb + ((size_t)(l0p+16+lo)*256 + sp)*256 + ks*32 + quad*8);
    bf16x8 gb[4];
    #pragma unroll
    for (int nt=0; nt<4; ++nt)
      gb[nt] = *(const bf16x8*)(Gw + (size_t)(wn0+nt*16+lo)*256 + ks*32 + quad*8);
    #pragma unroll
    for (int nt=0; nt<4; ++nt)
      gacc1[nt] = __builtin_amdgcn_mfma_f32_16x16x32_bf16(ga, gb[nt], gacc1[nt], 0,0,0);
  }
  __syncthreads();   // B4: OS half-1 visible
  #pragma unroll
  for (int nt=0; nt<4; ++nt){
    int n = wn0 + nt*16 + lo;
    float bgn = bg[n];
    #pragma unroll
    for (int r=0; r<4; ++r){
      int jj = quad*4 + r;
      int j = 16 + jj;                          // 16..31
      float g = 1.f/(1.f + __expf(-(gacc1[nt][r] + bgn)));
      int sidx = jj*8 + (n>>5);                 // row - 128
      GS[j*264 + n] = f2b(g * OS[sidx*32 + (n&31)]);
    }
  }
  __syncthreads();   // B5: GS fully written

  // ================= Phase 4: out projection [32 x 256] =====================
  const u16* Ow = WT + (size_t)4*65536;   // wo^T
  f32x4 pacc[2][4];
  #pragma unroll
  for (int a=0;a<2;++a)
    #pragma unroll
    for (int b=0;b<4;++b) pacc[a][b]=z4;
  for (int ks=0; ks<8; ++ks){
    bf16x8 pa[2];
    #pragma unroll
    for (int mt2=0; mt2<2; ++mt2)
      pa[mt2] = *(const bf16x8*)&GS[(mt2*16+lo)*264 + ks*32 + quad*8];
    bf16x8 pb[4];
    #pragma unroll
    for (int nt=0; nt<4; ++nt)
      pb[nt] = *(const bf16x8*)(Ow + (size_t)(wn0+nt*16+lo)*256 + ks*32 + quad*8);
    #pragma unroll
    for (int mt2=0; mt2<2; ++mt2)
      #pragma unroll
      for (int nt=0; nt<4; ++nt)
        pacc[mt2][nt] = __builtin_amdgcn_mfma_f32_16x16x32_bf16(pa[mt2], pb[nt], pacc[mt2][nt], 0,0,0);
  }
  #pragma unroll
  for (int nt=0; nt<4; ++nt){
    int n = wn0 + nt*16 + lo;
    float bon = bo[n];
    #pragma unroll
    for (int mt2=0; mt2<2; ++mt2)
      #pragma unroll
      for (int r=0; r<4; ++r){
        int j = mt2*16 + quad*4 + r;
        int sp2 = h*32 + (l>>3);
        outp[((size_t)sp2*256 + l0p + j)*256 + n] = pacc[mt2][nt][r] + bon;
      }
  }
}

extern "C" void kernel_launch(void* const* d_in, const int* in_sizes, int n_in,
                              void* d_out, int out_size, void* d_ws, size_t ws_size,
                              hipStream_t stream){
  const float* m  = (const float*)d_in[0];
  const float* lw = (const float*)d_in[1];
  const float* lb = (const float*)d_in[2];
  const float* wq = (const float*)d_in[3];
  const float* wk = (const float*)d_in[4];
  const float* wv = (const float*)d_in[5];
  const float* wg = (const float*)d_in[6];
  const float* bg = (const float*)d_in[7];
  const float* wo = (const float*)d_in[8];
  const float* bo = (const float*)d_in[9];

  // ws: mnb bf16 [l][s][cm] = 32 MiB | WT bf16 [5][256][256] = 640 KiB
  u16* mnb = (u16*)d_ws;
  u16* WT  = mnb + (size_t)16777216;
  float* out = (float*)d_out;

  k_wprep<<<dim3(16,5), 256, 0, stream>>>(wq, wk, wv, wg, wo, WT);
  k_ln   <<<2048,       256, 0, stream>>>(m, lw, lb, mnb);
  k_fused<<<2048,       256, 0, stream>>>(mnb, WT, bg, bo, out);
}

// Round 9
// 282.918 us; speedup vs baseline: 1.1638x; 1.1638x over previous
//
#include <hip/hip_runtime.h>

typedef unsigned short u16;
typedef __attribute__((ext_vector_type(8))) short bf16x8;   // 8 bf16 = 4 VGPR
typedef __attribute__((ext_vector_type(4))) float f32x4;

// Bit-math round-to-nearest-even f32->bf16. NOTE: empirically faster than the
// __bf16 cast path in this kernel (R6/R7 A/B: cast costs ~17us despite fewer
// VALU ops) -- do not "optimize" this back to the hardware cast.
__device__ __forceinline__ u16 f2b(float f){
  unsigned int u = __float_as_uint(f);
  u += 0x7fffu + ((u>>16)&1u);
  return (u16)(u>>16);
}

// ---- K1: LayerNorm over c_m -> bf16 mnb [l][s][cm].
// Orientation: block = (s, l-band of 32) => READS are contiguous (32KB/block
// streaming); the scattered 1KB@256KB-stride side is now the WRITE (non-
// stalling). R7's orientation had the scatter on the read side (~95us). ----
__global__ __launch_bounds__(256) void k_ln(const float* __restrict__ m,
    const float* __restrict__ lw, const float* __restrict__ lb,
    u16* __restrict__ mnb){
  int bx = blockIdx.x;                       // 2048 blocks
  int s = bx>>3;
  int l0 = (bx&7)*32 + (threadIdx.x>>6)*8;   // 4 waves x 8 l-rows
  int ln = threadIdx.x&63;
  float4 w = *(const float4*)(lw + ln*4);
  float4 b = *(const float4*)(lb + ln*4);
  #pragma unroll
  for (int i=0;i<8;++i){
    int l = l0 + i;
    float4 x = *(const float4*)(m + ((size_t)s*256 + l)*256 + ln*4);
    float s1 = x.x+x.y+x.z+x.w;
    float s2 = x.x*x.x + x.y*x.y + x.z*x.z + x.w*x.w;
    #pragma unroll
    for (int off=32; off>0; off>>=1){
      s1 += __shfl_xor(s1, off);
      s2 += __shfl_xor(s2, off);
    }
    float mu  = s1*(1.0f/256.0f);
    float inv = rsqrtf(s2*(1.0f/256.0f) - mu*mu + 1e-5f);
    u16 o[4];
    o[0] = f2b((x.x-mu)*inv*w.x + b.x);
    o[1] = f2b((x.y-mu)*inv*w.y + b.y);
    o[2] = f2b((x.z-mu)*inv*w.z + b.z);
    o[3] = f2b((x.w-mu)*inv*w.w + b.w);
    *(ushort4*)(mnb + ((size_t)l*256 + s)*256 + ln*4) = *(ushort4*)o;
  }
}

// ---- K0: pre-transpose weights to bf16 WT[z][n][cm], coalesced via LDS. ----
__global__ __launch_bounds__(256) void k_wprep(
    const float* __restrict__ wq, const float* __restrict__ wk,
    const float* __restrict__ wv, const float* __restrict__ wg,
    const float* __restrict__ wo, u16* __restrict__ WT){
  __shared__ u16 T[16*264];
  int z = blockIdx.y, n0 = blockIdx.x*16, tid = threadIdx.x;
  const float* W = (z==0)?wq:(z==1)?wk:(z==2)?wv:(z==3)?wg:wo;
  int nl = tid&15;
  #pragma unroll
  for (int i=0;i<16;++i){
    int cm = i*16 + (tid>>4);
    T[nl*264 + cm] = f2b(W[(size_t)cm*256 + n0 + nl]);   // 64B-coalesced reads
  }
  __syncthreads();
  int n = tid>>4, cc = (tid&15)*16;
  uint4 a = *(const uint4*)&T[n*264 + cc];
  uint4 c = *(const uint4*)&T[n*264 + cc + 8];
  *(uint4*)&WT[(size_t)z*65536 + (size_t)(n0+n)*256 + cc]     = a;
  *(uint4*)&WT[(size_t)z*65536 + (size_t)(n0+n)*256 + cc + 8] = c;
}

// ---- K2: fully fused per (l,h): QKV proj -> attention -> gate -> out proj ----
// Key identity: block (l,h) produces out rows (s'=32h+(l>>3), l'=(l&7)*32+j),
// and the scrambled o is O_flat[j][n] == o[s][c] at the SAME flat index
// (s*32+c == j*256+n), so gate+proj fuse with a pure reinterpret of o in LDS.
// == R2-verified kernel EXACTLY (177us; best measured). Do not restructure:
// R3 (reg-cap), R4 (mnb2), R5 (prefetch), R8 (LDS diet) all regressed. ==
__global__ __launch_bounds__(256,3) void k_fused(const u16* __restrict__ mnb,
    const u16* __restrict__ WT, const float* __restrict__ bg,
    const float* __restrict__ bo, float* __restrict__ outp){
  // LDS map (u16 units), total 26880 u16 = 53760 B -> 3 blocks/CU.
  //  QS [256][40] q[s][c]          :     0 .. 10239
  //  KS [256][32] k[t][c]          : 10240 .. 18431
  //  VT [32][264] v^T[c][t]        : 18432 .. 26879
  //  PB per-wave P [64][40]        : aliases QS (QS dead after qf reg-load)
  //  OS f32 [256][32] o            : aliases QS+KS region, after sync
  //  GS [32][264] gated bf16       : aliases VT region, after sync
  __shared__ u16 smem[26880];
  u16* QS = smem;
  u16* KS = smem + 10240;
  u16* VT = smem + 18432;
  u16* PB = smem;            // + wid*64*40 == QS per-wave region
  float* OS = (float*)smem;
  u16* GS = smem + 18432;

  int bx = blockIdx.x;
  // XCD-aware swizzle: XCD = bx%8; each XCD owns a contiguous 32-wide l-range,
  // 8 h-blocks per l adjacent in dispatch order.
  int l = ((bx&7)<<5) | (bx>>6);
  int h = (bx>>3)&7;
  int tid = threadIdx.x;
  int lane = tid&63, wid = tid>>6, quad = lane>>4, lo = lane&15;
  int m0 = wid*64;
  f32x4 z4 = {0.f,0.f,0.f,0.f};

  // ================= Phase 1: QKV projection (head h slice) =================
  const u16* Abase = mnb + (size_t)l*65536;          // mn_l [s][cm]
  const u16* Bq = WT + (size_t)h*32*256;
  const u16* Bk = WT + (size_t)65536 + (size_t)h*32*256;
  const u16* Bv = WT + (size_t)2*65536 + (size_t)h*32*256;
  f32x4 acc[4][6];                                   // nt: 0-1 q, 2-3 k, 4-5 v
  #pragma unroll
  for (int a=0;a<4;++a)
    #pragma unroll
    for (int b=0;b<6;++b) acc[a][b]=z4;

  for (int ks=0; ks<8; ++ks){
    bf16x8 af[4];
    #pragma unroll
    for (int mt=0; mt<4; ++mt)
      af[mt] = *(const bf16x8*)(Abase + (size_t)(m0+mt*16+lo)*256 + ks*32 + quad*8);
    bf16x8 bq[2], bk2[2], bv2[2];
    #pragma unroll
    for (int c2=0; c2<2; ++c2){
      bq[c2]  = *(const bf16x8*)(Bq + (size_t)(c2*16+lo)*256 + ks*32 + quad*8);
      bk2[c2] = *(const bf16x8*)(Bk + (size_t)(c2*16+lo)*256 + ks*32 + quad*8);
      bv2[c2] = *(const bf16x8*)(Bv + (size_t)(c2*16+lo)*256 + ks*32 + quad*8);
    }
    #pragma unroll
    for (int mt=0; mt<4; ++mt){
      #pragma unroll
      for (int c2=0; c2<2; ++c2){
        acc[mt][0+c2] = __builtin_amdgcn_mfma_f32_16x16x32_bf16(af[mt], bq[c2],  acc[mt][0+c2], 0,0,0);
        acc[mt][2+c2] = __builtin_amdgcn_mfma_f32_16x16x32_bf16(af[mt], bk2[c2], acc[mt][2+c2], 0,0,0);
        acc[mt][4+c2] = __builtin_amdgcn_mfma_f32_16x16x32_bf16(af[mt], bv2[c2], acc[mt][4+c2], 0,0,0);
      }
    }
  }
  // scatter q,k (row-major) and v (transposed) to LDS
  #pragma unroll
  for (int mt=0; mt<4; ++mt)
    #pragma unroll
    for (int ntl=0; ntl<2; ++ntl)
      #pragma unroll
      for (int r=0; r<4; ++r){
        int s = m0 + mt*16 + quad*4 + r;
        QS[s*40 + ntl*16+lo] = f2b(acc[mt][0+ntl][r]);
        KS[s*32 + ntl*16+lo] = f2b(acc[mt][2+ntl][r]);
        VT[(ntl*16+lo)*264 + s] = f2b(acc[mt][4+ntl][r]);
      }
  // q-frags are own-wave rows: load before the barrier (QS dead afterwards,
  // so PB can alias it)
  bf16x8 qf[4];
  #pragma unroll
  for (int mt=0; mt<4; ++mt)
    qf[mt] = *(const bf16x8*)&QS[(m0+mt*16+lo)*40 + quad*8];
  __syncthreads();   // B0: KS/VT visible to all waves

  // ================= Phase 2: attention =====================================
  const float scale = 0.17677669529663687f;  // 1/sqrt(32)
  float lr[16];
  #pragma unroll
  for (int i=0;i<16;++i) lr[i]=0.f;
  f32x4 o_acc[4][2];
  #pragma unroll
  for (int a=0;a<4;++a){ o_acc[a][0]=z4; o_acc[a][1]=z4; }
  int pbase = wid*64*40;

  for (int ts=0; ts<8; ++ts){
    bf16x8 kf[2];
    #pragma unroll
    for (int ntl=0; ntl<2; ++ntl)
      kf[ntl] = *(const bf16x8*)&KS[(ts*32+ntl*16+lo)*32 + quad*8];
    bf16x8 vf[2];
    #pragma unroll
    for (int nc=0; nc<2; ++nc)
      vf[nc] = *(const bf16x8*)&VT[(nc*16+lo)*264 + ts*32 + quad*8];
    #pragma unroll
    for (int mt=0; mt<4; ++mt){
      f32x4 sa[2];
      sa[0] = __builtin_amdgcn_mfma_f32_16x16x32_bf16(qf[mt], kf[0], z4, 0,0,0);
      sa[1] = __builtin_amdgcn_mfma_f32_16x16x32_bf16(qf[mt], kf[1], z4, 0,0,0);
      #pragma unroll
      for (int ntl=0; ntl<2; ++ntl)
        #pragma unroll
        for (int r=0; r<4; ++r){
          float p = __expf(sa[ntl][r]*scale);
          lr[mt*4+r] += p;
          PB[pbase + (mt*16+quad*4+r)*40 + ntl*16+lo] = f2b(p);
        }
      bf16x8 paf = *(const bf16x8*)&PB[pbase + (mt*16+lo)*40 + quad*8];
      o_acc[mt][0] = __builtin_amdgcn_mfma_f32_16x16x32_bf16(paf, vf[0], o_acc[mt][0], 0,0,0);
      o_acc[mt][1] = __builtin_amdgcn_mfma_f32_16x16x32_bf16(paf, vf[1], o_acc[mt][1], 0,0,0);
    }
  }
  #pragma unroll
  for (int i=0;i<16;++i){
    float v = lr[i];
    v += __shfl_xor(v, 1);
    v += __shfl_xor(v, 2);
    v += __shfl_xor(v, 4);
    v += __shfl_xor(v, 8);
    lr[i] = 1.0f / v;
  }
  __syncthreads();   // B1: all waves done reading KS/VT/PB before OS overwrites
  // o stays f32 in LDS (no extra rounding vs verified pipeline)
  #pragma unroll
  for (int mt=0; mt<4; ++mt)
    #pragma unroll
    for (int nc=0; nc<2; ++nc)
      #pragma unroll
      for (int r=0; r<4; ++r){
        int s = m0 + mt*16 + quad*4 + r;
        int c = nc*16 + lo;
        OS[s*32 + c] = o_acc[mt][nc][r] * lr[mt*4+r];
      }
  __syncthreads();   // B2: OS visible

  // ================= Phase 3: gate GEMM [32 x 256] ==========================
  int sp  = h*32 + (l>>3);      // s' (constant per block)
  int l0p = (l&7)*32;           // l' base; rows j = 0..31
  int wn0 = wid*64;             // this wave's 64-col slice of n
  const u16* Gw = WT + (size_t)3*65536;   // wg^T [n][cm]
  f32x4 gacc[2][4];
  #pragma unroll
  for (int a=0;a<2;++a)
    #pragma unroll
    for (int b=0;b<4;++b) gacc[a][b]=z4;
  for (int ks=0; ks<8; ++ks){
    bf16x8 ga[2];
    #pragma unroll
    for (int mt2=0; mt2<2; ++mt2)
      ga[mt2] = *(const bf16x8*)(mnb + ((size_t)(l0p+mt2*16+lo)*256 + sp)*256 + ks*32 + quad*8);
    bf16x8 gb[4];
    #pragma unroll
    for (int nt=0; nt<4; ++nt)
      gb[nt] = *(const bf16x8*)(Gw + (size_t)(wn0+nt*16+lo)*256 + ks*32 + quad*8);
    #pragma unroll
    for (int mt2=0; mt2<2; ++mt2)
      #pragma unroll
      for (int nt=0; nt<4; ++nt)
        gacc[mt2][nt] = __builtin_amdgcn_mfma_f32_16x16x32_bf16(ga[mt2], gb[nt], gacc[mt2][nt], 0,0,0);
  }
  // sigmoid, multiply by O_flat (pure reinterpret of OS), store bf16 to GS
  #pragma unroll
  for (int nt=0; nt<4; ++nt){
    int n = wn0 + nt*16 + lo;
    float bgn = bg[n];
    #pragma unroll
    for (int mt2=0; mt2<2; ++mt2)
      #pragma unroll
      for (int r=0; r<4; ++r){
        int j = mt2*16 + quad*4 + r;
        float g = 1.f/(1.f + __expf(-(gacc[mt2][nt][r] + bgn)));
        GS[j*264 + n] = f2b(g * OS[j*256 + n]);
      }
  }
  __syncthreads();   // B3: GS visible

  // ================= Phase 4: out projection [32 x 256] =====================
  const u16* Ow = WT + (size_t)4*65536;   // wo^T
  f32x4 pacc[2][4];
  #pragma unroll
  for (int a=0;a<2;++a)
    #pragma unroll
    for (int b=0;b<4;++b) pacc[a][b]=z4;
  for (int ks=0; ks<8; ++ks){
    bf16x8 pa[2];
    #pragma unroll
    for (int mt2=0; mt2<2; ++mt2)
      pa[mt2] = *(const bf16x8*)&GS[(mt2*16+lo)*264 + ks*32 + quad*8];
    bf16x8 pb[4];
    #pragma unroll
    for (int nt=0; nt<4; ++nt)
      pb[nt] = *(const bf16x8*)(Ow + (size_t)(wn0+nt*16+lo)*256 + ks*32 + quad*8);
    #pragma unroll
    for (int mt2=0; mt2<2; ++mt2)
      #pragma unroll
      for (int nt=0; nt<4; ++nt)
        pacc[mt2][nt] = __builtin_amdgcn_mfma_f32_16x16x32_bf16(pa[mt2], pb[nt], pacc[mt2][nt], 0,0,0);
  }
  #pragma unroll
  for (int nt=0; nt<4; ++nt){
    int n = wn0 + nt*16 + lo;
    float bon = bo[n];
    #pragma unroll
    for (int mt2=0; mt2<2; ++mt2)
      #pragma unroll
      for (int r=0; r<4; ++r){
        int j = mt2*16 + quad*4 + r;
        outp[((size_t)sp*256 + l0p + j)*256 + n] = pacc[mt2][nt][r] + bon;
      }
  }
}

extern "C" void kernel_launch(void* const* d_in, const int* in_sizes, int n_in,
                              void* d_out, int out_size, void* d_ws, size_t ws_size,
                              hipStream_t stream){
  const float* m  = (const float*)d_in[0];
  const float* lw = (const float*)d_in[1];
  const float* lb = (const float*)d_in[2];
  const float* wq = (const float*)d_in[3];
  const float* wk = (const float*)d_in[4];
  const float* wv = (const float*)d_in[5];
  const float* wg = (const float*)d_in[6];
  const float* bg = (const float*)d_in[7];
  const float* wo = (const float*)d_in[8];
  const float* bo = (const float*)d_in[9];

  // ws: mnb bf16 [l][s][cm] = 32 MiB | WT bf16 [5][256][256] = 640 KiB
  u16* mnb = (u16*)d_ws;
  u16* WT  = mnb + (size_t)16777216;
  float* out = (float*)d_out;

  k_wprep<<<dim3(16,5), 256, 0, stream>>>(wq, wk, wv, wg, wo, WT);
  k_ln   <<<2048,       256, 0, stream>>>(m, lw, lb, mnb);
  k_fused<<<2048,       256, 0, stream>>>(mnb, WT, bg, bo, out);
}

// Round 10
// 278.753 us; speedup vs baseline: 1.1811x; 1.0149x over previous
//
#include <hip/hip_runtime.h>

typedef unsigned short u16;
typedef __attribute__((ext_vector_type(8))) short bf16x8;   // 8 bf16 = 4 VGPR
typedef __attribute__((ext_vector_type(4))) float f32x4;

// Bit-math round-to-nearest-even f32->bf16. NOTE: empirically faster than the
// __bf16 cast path in this kernel (R6/R7 A/B: cast costs ~17us despite fewer
// VALU ops) -- do not "optimize" this back to the hardware cast.
__device__ __forceinline__ u16 f2b(float f){
  unsigned int u = __float_as_uint(f);
  u += 0x7fffu + ((u>>16)&1u);
  return (u16)(u>>16);
}

// ---- K1: prep. bx<2048: LayerNorm -> bf16 mnb [l][s][cm] (R9-proven body,
// contiguous reads). bx>=2048: weight transpose to bf16 WT[z][n][cm]. ----
__global__ __launch_bounds__(256) void k_pre(const float* __restrict__ m,
    const float* __restrict__ lw, const float* __restrict__ lb,
    const float* __restrict__ wq, const float* __restrict__ wk,
    const float* __restrict__ wv, const float* __restrict__ wg,
    const float* __restrict__ wo,
    u16* __restrict__ mnb, u16* __restrict__ WT){
  __shared__ u16 T[16*264];
  int bx = blockIdx.x, tid = threadIdx.x;
  if (bx < 2048){
    int s = bx>>3;
    int l0 = (bx&7)*32 + (tid>>6)*8;   // 4 waves x 8 l-rows
    int ln = tid&63;
    float4 w = *(const float4*)(lw + ln*4);
    float4 b = *(const float4*)(lb + ln*4);
    #pragma unroll
    for (int i=0;i<8;++i){
      int l = l0 + i;
      float4 x = *(const float4*)(m + ((size_t)s*256 + l)*256 + ln*4);
      float s1 = x.x+x.y+x.z+x.w;
      float s2 = x.x*x.x + x.y*x.y + x.z*x.z + x.w*x.w;
      #pragma unroll
      for (int off=32; off>0; off>>=1){
        s1 += __shfl_xor(s1, off);
        s2 += __shfl_xor(s2, off);
      }
      float mu  = s1*(1.0f/256.0f);
      float inv = rsqrtf(s2*(1.0f/256.0f) - mu*mu + 1e-5f);
      u16 o[4];
      o[0] = f2b((x.x-mu)*inv*w.x + b.x);
      o[1] = f2b((x.y-mu)*inv*w.y + b.y);
      o[2] = f2b((x.z-mu)*inv*w.z + b.z);
      o[3] = f2b((x.w-mu)*inv*w.w + b.w);
      *(ushort4*)(mnb + ((size_t)l*256 + s)*256 + ln*4) = *(ushort4*)o;
    }
  } else {
    // Weight transpose: 80 blocks; z = 0..4 (wq,wk,wv,wg,wo), 16 n-cols each.
    int bb = bx - 2048;
    int z = bb>>4, n0 = (bb&15)*16;
    const float* W = (z==0)?wq:(z==1)?wk:(z==2)?wv:(z==3)?wg:wo;
    int nl = tid&15;
    #pragma unroll
    for (int i=0;i<16;++i){
      int cm = i*16 + (tid>>4);
      T[nl*264 + cm] = f2b(W[(size_t)cm*256 + n0 + nl]);   // 64B-coalesced reads
    }
    __syncthreads();
    int n = tid>>4, cc = (tid&15)*16;
    uint4 a = *(const uint4*)&T[n*264 + cc];
    uint4 c = *(const uint4*)&T[n*264 + cc + 8];
    *(uint4*)&WT[(size_t)z*65536 + (size_t)(n0+n)*256 + cc]     = a;
    *(uint4*)&WT[(size_t)z*65536 + (size_t)(n0+n)*256 + cc + 8] = c;
  }
}

// ---- K2: fully fused per (l,h): QKV proj -> attention -> gate -> out proj ----
// Key identity: block (l,h) produces out rows (s'=32h+(l>>3), l'=(l&7)*32+j),
// and the scrambled o is O_flat[j][n] == o[s][c] at the SAME flat index
// (s*32+c == j*256+n), so gate+proj fuse with a pure reinterpret of o in LDS.
// == R2-verified structure (177us). Single delta this round: KS XOR-swizzle
// (col-block ^= (row>>2)&3) -- 8-way -> 2-way ds_read_b128 bank conflicts.
// Do not restructure: R3 (reg-cap), R4 (mnb2), R5 (prefetch), R8 (LDS diet)
// all regressed. ==
__global__ __launch_bounds__(256,3) void k_fused(const u16* __restrict__ mnb,
    const u16* __restrict__ WT, const float* __restrict__ bg,
    const float* __restrict__ bo, float* __restrict__ outp){
  // LDS map (u16 units), total 26880 u16 = 53760 B -> 3 blocks/CU.
  //  QS [256][40] q[s][c]          :     0 .. 10239
  //  KS [256][32] k[t][c] swizzled : 10240 .. 18431
  //  VT [32][264] v^T[c][t]        : 18432 .. 26879
  //  PB per-wave P [64][40]        : aliases QS (QS dead after qf reg-load)
  //  OS f32 [256][32] o            : aliases QS+KS region, after sync
  //  GS [32][264] gated bf16       : aliases VT region, after sync
  __shared__ u16 smem[26880];
  u16* QS = smem;
  u16* KS = smem + 10240;
  u16* VT = smem + 18432;
  u16* PB = smem;            // + wid*64*40 == QS per-wave region
  float* OS = (float*)smem;
  u16* GS = smem + 18432;

  int bx = blockIdx.x;
  // XCD-aware swizzle: XCD = bx%8; each XCD owns a contiguous 32-wide l-range,
  // 8 h-blocks per l adjacent in dispatch order.
  int l = ((bx&7)<<5) | (bx>>6);
  int h = (bx>>3)&7;
  int tid = threadIdx.x;
  int lane = tid&63, wid = tid>>6, quad = lane>>4, lo = lane&15;
  int m0 = wid*64;
  f32x4 z4 = {0.f,0.f,0.f,0.f};

  // ================= Phase 1: QKV projection (head h slice) =================
  const u16* Abase = mnb + (size_t)l*65536;          // mn_l [s][cm]
  const u16* Bq = WT + (size_t)h*32*256;
  const u16* Bk = WT + (size_t)65536 + (size_t)h*32*256;
  const u16* Bv = WT + (size_t)2*65536 + (size_t)h*32*256;
  f32x4 acc[4][6];                                   // nt: 0-1 q, 2-3 k, 4-5 v
  #pragma unroll
  for (int a=0;a<4;++a)
    #pragma unroll
    for (int b=0;b<6;++b) acc[a][b]=z4;

  for (int ks=0; ks<8; ++ks){
    bf16x8 af[4];
    #pragma unroll
    for (int mt=0; mt<4; ++mt)
      af[mt] = *(const bf16x8*)(Abase + (size_t)(m0+mt*16+lo)*256 + ks*32 + quad*8);
    bf16x8 bq[2], bk2[2], bv2[2];
    #pragma unroll
    for (int c2=0; c2<2; ++c2){
      bq[c2]  = *(const bf16x8*)(Bq + (size_t)(c2*16+lo)*256 + ks*32 + quad*8);
      bk2[c2] = *(const bf16x8*)(Bk + (size_t)(c2*16+lo)*256 + ks*32 + quad*8);
      bv2[c2] = *(const bf16x8*)(Bv + (size_t)(c2*16+lo)*256 + ks*32 + quad*8);
    }
    #pragma unroll
    for (int mt=0; mt<4; ++mt){
      #pragma unroll
      for (int c2=0; c2<2; ++c2){
        acc[mt][0+c2] = __builtin_amdgcn_mfma_f32_16x16x32_bf16(af[mt], bq[c2],  acc[mt][0+c2], 0,0,0);
        acc[mt][2+c2] = __builtin_amdgcn_mfma_f32_16x16x32_bf16(af[mt], bk2[c2], acc[mt][2+c2], 0,0,0);
        acc[mt][4+c2] = __builtin_amdgcn_mfma_f32_16x16x32_bf16(af[mt], bv2[c2], acc[mt][4+c2], 0,0,0);
      }
    }
  }
  // scatter q,k (row-major) and v (transposed) to LDS.
  // KS element (row s, col c) stored at col' = c ^ (((s>>2)&3)<<3); here
  // (s>>2)&3 == quad (s = 64*wid + 16*mt + 4*quad + r, r<4).
  #pragma unroll
  for (int mt=0; mt<4; ++mt)
    #pragma unroll
    for (int ntl=0; ntl<2; ++ntl)
      #pragma unroll
      for (int r=0; r<4; ++r){
        int s = m0 + mt*16 + quad*4 + r;
        QS[s*40 + ntl*16+lo] = f2b(acc[mt][0+ntl][r]);
        KS[s*32 + ((ntl*16+lo) ^ (quad<<3))] = f2b(acc[mt][2+ntl][r]);
        VT[(ntl*16+lo)*264 + s] = f2b(acc[mt][4+ntl][r]);
      }
  // q-frags are own-wave rows: load before the barrier (QS dead afterwards,
  // so PB can alias it)
  bf16x8 qf[4];
  #pragma unroll
  for (int mt=0; mt<4; ++mt)
    qf[mt] = *(const bf16x8*)&QS[(m0+mt*16+lo)*40 + quad*8];
  __syncthreads();   // B0: KS/VT visible to all waves

  // ================= Phase 2: attention =====================================
  const float scale = 0.17677669529663687f;  // 1/sqrt(32)
  float lr[16];
  #pragma unroll
  for (int i=0;i<16;++i) lr[i]=0.f;
  f32x4 o_acc[4][2];
  #pragma unroll
  for (int a=0;a<4;++a){ o_acc[a][0]=z4; o_acc[a][1]=z4; }
  int pbase = wid*64*40;

  for (int ts=0; ts<8; ++ts){
    bf16x8 kf[2];
    #pragma unroll
    for (int ntl=0; ntl<2; ++ntl){
      // row t = ts*32+ntl*16+lo; (t>>2)&3 == (lo>>2)&3 -> same involution as
      // the write side; 8-u16 block stays contiguous (XOR on bits 3-4 only).
      kf[ntl] = *(const bf16x8*)&KS[(ts*32+ntl*16+lo)*32 + ((quad*8) ^ (((lo>>2)&3)<<3))];
    }
    bf16x8 vf[2];
    #pragma unroll
    for (int nc=0; nc<2; ++nc)
      vf[nc] = *(const bf16x8*)&VT[(nc*16+lo)*264 + ts*32 + quad*8];
    #pragma unroll
    for (int mt=0; mt<4; ++mt){
      f32x4 sa[2];
      sa[0] = __builtin_amdgcn_mfma_f32_16x16x32_bf16(qf[mt], kf[0], z4, 0,0,0);
      sa[1] = __builtin_amdgcn_mfma_f32_16x16x32_bf16(qf[mt], kf[1], z4, 0,0,0);
      #pragma unroll
      for (int ntl=0; ntl<2; ++ntl)
        #pragma unroll
        for (int r=0; r<4; ++r){
          float p = __expf(sa[ntl][r]*scale);
          lr[mt*4+r] += p;
          PB[pbase + (mt*16+quad*4+r)*40 + ntl*16+lo] = f2b(p);
        }
      bf16x8 paf = *(const bf16x8*)&PB[pbase + (mt*16+lo)*40 + quad*8];
      o_acc[mt][0] = __builtin_amdgcn_mfma_f32_16x16x32_bf16(paf, vf[0], o_acc[mt][0], 0,0,0);
      o_acc[mt][1] = __builtin_amdgcn_mfma_f32_16x16x32_bf16(paf, vf[1], o_acc[mt][1], 0,0,0);
    }
  }
  #pragma unroll
  for (int i=0;i<16;++i){
    float v = lr[i];
    v += __shfl_xor(v, 1);
    v += __shfl_xor(v, 2);
    v += __shfl_xor(v, 4);
    v += __shfl_xor(v, 8);
    lr[i] = 1.0f / v;
  }
  __syncthreads();   // B1: all waves done reading KS/VT/PB before OS overwrites
  // o stays f32 in LDS (no extra rounding vs verified pipeline)
  #pragma unroll
  for (int mt=0; mt<4; ++mt)
    #pragma unroll
    for (int nc=0; nc<2; ++nc)
      #pragma unroll
      for (int r=0; r<4; ++r){
        int s = m0 + mt*16 + quad*4 + r;
        int c = nc*16 + lo;
        OS[s*32 + c] = o_acc[mt][nc][r] * lr[mt*4+r];
      }
  __syncthreads();   // B2: OS visible

  // ================= Phase 3: gate GEMM [32 x 256] ==========================
  int sp  = h*32 + (l>>3);      // s' (constant per block)
  int l0p = (l&7)*32;           // l' base; rows j = 0..31
  int wn0 = wid*64;             // this wave's 64-col slice of n
  const u16* Gw = WT + (size_t)3*65536;   // wg^T [n][cm]
  f32x4 gacc[2][4];
  #pragma unroll
  for (int a=0;a<2;++a)
    #pragma unroll
    for (int b=0;b<4;++b) gacc[a][b]=z4;
  for (int ks=0; ks<8; ++ks){
    bf16x8 ga[2];
    #pragma unroll
    for (int mt2=0; mt2<2; ++mt2)
      ga[mt2] = *(const bf16x8*)(mnb + ((size_t)(l0p+mt2*16+lo)*256 + sp)*256 + ks*32 + quad*8);
    bf16x8 gb[4];
    #pragma unroll
    for (int nt=0; nt<4; ++nt)
      gb[nt] = *(const bf16x8*)(Gw + (size_t)(wn0+nt*16+lo)*256 + ks*32 + quad*8);
    #pragma unroll
    for (int mt2=0; mt2<2; ++mt2)
      #pragma unroll
      for (int nt=0; nt<4; ++nt)
        gacc[mt2][nt] = __builtin_amdgcn_mfma_f32_16x16x32_bf16(ga[mt2], gb[nt], gacc[mt2][nt], 0,0,0);
  }
  // sigmoid, multiply by O_flat (pure reinterpret of OS), store bf16 to GS
  #pragma unroll
  for (int nt=0; nt<4; ++nt){
    int n = wn0 + nt*16 + lo;
    float bgn = bg[n];
    #pragma unroll
    for (int mt2=0; mt2<2; ++mt2)
      #pragma unroll
      for (int r=0; r<4; ++r){
        int j = mt2*16 + quad*4 + r;
        float g = 1.f/(1.f + __expf(-(gacc[mt2][nt][r] + bgn)));
        GS[j*264 + n] = f2b(g * OS[j*256 + n]);
      }
  }
  __syncthreads();   // B3: GS visible

  // ================= Phase 4: out projection [32 x 256] =====================
  const u16* Ow = WT + (size_t)4*65536;   // wo^T
  f32x4 pacc[2][4];
  #pragma unroll
  for (int a=0;a<2;++a)
    #pragma unroll
    for (int b=0;b<4;++b) pacc[a][b]=z4;
  for (int ks=0; ks<8; ++ks){
    bf16x8 pa[2];
    #pragma unroll
    for (int mt2=0; mt2<2; ++mt2)
      pa[mt2] = *(const bf16x8*)&GS[(mt2*16+lo)*264 + ks*32 + quad*8];
    bf16x8 pb[4];
    #pragma unroll
    for (int nt=0; nt<4; ++nt)
      pb[nt] = *(const bf16x8*)(Ow + (size_t)(wn0+nt*16+lo)*256 + ks*32 + quad*8);
    #pragma unroll
    for (int mt2=0; mt2<2; ++mt2)
      #pragma unroll
      for (int nt=0; nt<4; ++nt)
        pacc[mt2][nt] = __builtin_amdgcn_mfma_f32_16x16x32_bf16(pa[mt2], pb[nt], pacc[mt2][nt], 0,0,0);
  }
  #pragma unroll
  for (int nt=0; nt<4; ++nt){
    int n = wn0 + nt*16 + lo;
    float bon = bo[n];
    #pragma unroll
    for (int mt2=0; mt2<2; ++mt2)
      #pragma unroll
      for (int r=0; r<4; ++r){
        int j = mt2*16 + quad*4 + r;
        outp[((size_t)sp*256 + l0p + j)*256 + n] = pacc[mt2][nt][r] + bon;
      }
  }
}

extern "C" void kernel_launch(void* const* d_in, const int* in_sizes, int n_in,
                              void* d_out, int out_size, void* d_ws, size_t ws_size,
                              hipStream_t stream){
  const float* m  = (const float*)d_in[0];
  const float* lw = (const float*)d_in[1];
  const float* lb = (const float*)d_in[2];
  const float* wq = (const float*)d_in[3];
  const float* wk = (const float*)d_in[4];
  const float* wv = (const float*)d_in[5];
  const float* wg = (const float*)d_in[6];
  const float* bg = (const float*)d_in[7];
  const float* wo = (const float*)d_in[8];
  const float* bo = (const float*)d_in[9];

  // ws: mnb bf16 [l][s][cm] = 32 MiB | WT bf16 [5][256][256] = 640 KiB
  u16* mnb = (u16*)d_ws;
  u16* WT  = mnb + (size_t)16777216;
  float* out = (float*)d_out;

  k_pre  <<<2128, 256, 0, stream>>>(m, lw, lb, wq, wk, wv, wg, wo, mnb, WT);
  k_fused<<<2048, 256, 0, stream>>>(mnb, WT, bg, bo, out);
}